// Round 1
// baseline (880.588 us; speedup 1.0000x reference)
//
#include <hip/hip_runtime.h>
#include <hip/hip_bf16.h>
#include <math.h>

#define B_TOK 8192
#define D_DIM 1024
#define H_DIM 4096
#define E_NUM 8
#define NPAIR (B_TOK * 2)

typedef __bf16 bf16x8 __attribute__((ext_vector_type(8)));
typedef float f32x4 __attribute__((ext_vector_type(4)));
typedef unsigned short us4 __attribute__((ext_vector_type(4)));

__device__ __forceinline__ unsigned short f2bf(float f) {
  union { float f; unsigned u; } v; v.f = f;
  unsigned r = v.u + 0x7FFFu + ((v.u >> 16) & 1u);
  return (unsigned short)(r >> 16);
}

__device__ __forceinline__ void gload16(const void* g, void* l) {
  __builtin_amdgcn_global_load_lds(
      (const __attribute__((address_space(1))) void*)g,
      (__attribute__((address_space(3))) void*)l, 16, 0, 0);
}

// ---------------- x fp32 -> bf16 ----------------
__global__ void k_convert_x(const float* __restrict__ x, unsigned short* __restrict__ xb) {
  int i = (blockIdx.x * 256 + threadIdx.x) * 4;
  float4 v = *(const float4*)(x + i);
  us4 o;
  o[0] = f2bf(v.x); o[1] = f2bf(v.y); o[2] = f2bf(v.z); o[3] = f2bf(v.w);
  *(us4*)(xb + i) = o;
}

// -------- (E, rows, cols) fp32 -> (E, cols, rows) bf16 --------
__global__ void k_transpose_bf16(const float* __restrict__ in, unsigned short* __restrict__ out,
                                 int rows, int cols) {
  __shared__ float t[32][33];
  const float* ine = in + (size_t)blockIdx.z * rows * cols;
  unsigned short* oute = out + (size_t)blockIdx.z * rows * cols;
  int c0 = blockIdx.x * 32, r0 = blockIdx.y * 32;
  int tx = threadIdx.x, ty = threadIdx.y;
#pragma unroll
  for (int j = 0; j < 32; j += 8)
    t[ty + j][tx] = ine[(size_t)(r0 + ty + j) * cols + c0 + tx];
  __syncthreads();
#pragma unroll
  for (int j = 0; j < 32; j += 8)
    oute[(size_t)(c0 + ty + j) * rows + r0 + tx] = f2bf(t[tx][ty + j]);
}

// ---------------- router: logits, top-2, softmax ----------------
__global__ void k_router(const float* __restrict__ x, const float* __restrict__ wg,
                         const float* __restrict__ bg, int* __restrict__ tidx,
                         float* __restrict__ tgate, int* __restrict__ cnt) {
  int wid = threadIdx.x >> 6, lane = threadIdx.x & 63;
  int t = blockIdx.x * 4 + wid;
  float acc[E_NUM];
#pragma unroll
  for (int e = 0; e < E_NUM; e++) acc[e] = 0.f;
  const float* xr = x + (size_t)t * D_DIM;
  for (int i = lane; i < D_DIM; i += 64) {
    float xv = xr[i];
#pragma unroll
    for (int e = 0; e < E_NUM; e++) acc[e] += xv * wg[e * D_DIM + i];
  }
#pragma unroll
  for (int e = 0; e < E_NUM; e++) {
#pragma unroll
    for (int off = 32; off; off >>= 1) acc[e] += __shfl_xor(acc[e], off);
  }
  if (lane == 0) {
    float v[E_NUM];
#pragma unroll
    for (int e = 0; e < E_NUM; e++) v[e] = acc[e] + bg[e];
    int i0 = 0; float v0 = v[0];
#pragma unroll
    for (int e = 1; e < E_NUM; e++) if (v[e] > v0) { v0 = v[e]; i0 = e; }
    int i1 = -1; float v1 = -1e30f;
#pragma unroll
    for (int e = 0; e < E_NUM; e++) if (e != i0 && v[e] > v1) { v1 = v[e]; i1 = e; }
    float g0 = 1.f / (1.f + expf(v1 - v0));
    float g1 = 1.f - g0;
    tidx[2 * t] = i0; tidx[2 * t + 1] = i1;
    tgate[2 * t] = g0; tgate[2 * t + 1] = g1;
    atomicAdd(cnt + i0, 1);
    atomicAdd(cnt + i1, 1);
  }
}

__global__ void k_prefix(const int* __restrict__ cnt, int* __restrict__ eoff,
                         int* __restrict__ cursor) {
  if (threadIdx.x == 0) {
    int a = 0;
    for (int e = 0; e < E_NUM; e++) { eoff[e] = a; cursor[e] = a; a += cnt[e]; }
    eoff[E_NUM] = a;
  }
}

__global__ void k_scatter(const int* __restrict__ tidx, const float* __restrict__ tgate,
                          int* __restrict__ cursor, int* __restrict__ ptok,
                          float* __restrict__ pgate) {
  int t = blockIdx.x * 256 + threadIdx.x;
#pragma unroll
  for (int k = 0; k < 2; k++) {
    int e = tidx[2 * t + k];
    int p = atomicAdd(cursor + e, 1);
    ptok[p] = t;
    pgate[p] = tgate[2 * t + k];
  }
}

// ---------------- grouped GEMM (m97 structure) ----------------
// MODE 1: A = xb gathered via ptok, out = relu(A@B^T + b1) -> Hbuf (bf16)
// MODE 2: A = Hbuf rows direct,   out = (A@B^T + b2)*gate atomicAdd-> Out
template <int KDIM, int NDIM, int MODE>
__global__ __launch_bounds__(256, 2) void k_gemm(
    const unsigned short* __restrict__ A, const unsigned short* __restrict__ Bt,
    const float* __restrict__ bias, const int* __restrict__ eoff,
    const int* __restrict__ ptok, const float* __restrict__ pgate,
    unsigned short* __restrict__ Hout, float* __restrict__ Out) {
  constexpr int NT = NDIM / 128;
  constexpr int MT_MAX = NPAIR / 128;
  int bid = blockIdx.x;
  int e = bid / (MT_MAX * NT);
  int rem = bid - e * (MT_MAX * NT);
  int mt = rem / NT;
  int nt = rem - mt * NT;
  int off = eoff[e];
  int cnt = eoff[e + 1] - off;
  int m0 = mt * 128;
  if (m0 >= cnt) return;

  __shared__ unsigned short lA[128 * 32];
  __shared__ unsigned short lB[128 * 32];

  int tid = threadIdx.x;
  int w = tid >> 6, lane = tid & 63;
  int wm = w >> 1, wn = w & 1;

  // staging sources: chunk q = w*2+c covers rows q*16..q*16+15, lane covers
  // row q*16+(lane>>2), 16B segment (lane&3)  [HW: LDS dst = base + lane*16]
  const unsigned short* aSrc[2];
  const unsigned short* bSrc[2];
#pragma unroll
  for (int c = 0; c < 2; c++) {
    int q = w * 2 + c;
    int lrow = q * 16 + (lane >> 2);
    int arow = m0 + lrow;
    int ar = (arow < cnt) ? arow : (cnt - 1);
    size_t grow;
    if (MODE == 1) grow = (size_t)ptok[off + ar];
    else grow = (size_t)(off + ar);
    aSrc[c] = A + grow * KDIM + (lane & 3) * 8;
    int nrow = nt * 128 + q * 16 + (lane >> 2);
    bSrc[c] = Bt + (size_t)e * NDIM * KDIM + (size_t)nrow * KDIM + (lane & 3) * 8;
  }

  f32x4 acc[4][4] = {};
  for (int k0 = 0; k0 < KDIM; k0 += 32) {
#pragma unroll
    for (int c = 0; c < 2; c++) {
      int q = w * 2 + c;
      gload16(aSrc[c] + k0, &lA[q * 512]);
      gload16(bSrc[c] + k0, &lB[q * 512]);
    }
    __syncthreads();
    bf16x8 aF[4], bF[4];
#pragma unroll
    for (int m = 0; m < 4; m++) {
      int row = wm * 64 + m * 16 + (lane & 15);
      aF[m] = *(const bf16x8*)&lA[row * 32 + (lane >> 4) * 8];
    }
#pragma unroll
    for (int n = 0; n < 4; n++) {
      int row = wn * 64 + n * 16 + (lane & 15);
      bF[n] = *(const bf16x8*)&lB[row * 32 + (lane >> 4) * 8];
    }
#pragma unroll
    for (int m = 0; m < 4; m++)
#pragma unroll
      for (int n = 0; n < 4; n++)
        acc[m][n] = __builtin_amdgcn_mfma_f32_16x16x32_bf16(aF[m], bF[n], acc[m][n], 0, 0, 0);
    __syncthreads();
  }

  // epilogue: C/D map col=lane&15, row=(lane>>4)*4+r
#pragma unroll
  for (int m = 0; m < 4; m++) {
    int lrowb = wm * 64 + m * 16 + (lane >> 4) * 4;
#pragma unroll
    for (int r = 0; r < 4; r++) {
      int arow = m0 + lrowb + r;
      if (arow < cnt) {
        if constexpr (MODE == 1) {
          size_t rowbase = (size_t)(off + arow) * NDIM;
#pragma unroll
          for (int n = 0; n < 4; n++) {
            int col = nt * 128 + wn * 64 + n * 16 + (lane & 15);
            float v = acc[m][n][r] + bias[e * NDIM + col];
            v = v > 0.f ? v : 0.f;
            Hout[rowbase + col] = f2bf(v);
          }
        } else {
          int tok = ptok[off + arow];
          float g = pgate[off + arow];
#pragma unroll
          for (int n = 0; n < 4; n++) {
            int col = nt * 128 + wn * 64 + n * 16 + (lane & 15);
            float v = (acc[m][n][r] + bias[e * NDIM + col]) * g;
            atomicAdd(Out + (size_t)tok * D_DIM + col, v);
          }
        }
      }
    }
  }
}

extern "C" void kernel_launch(void* const* d_in, const int* in_sizes, int n_in,
                              void* d_out, int out_size, void* d_ws, size_t ws_size,
                              hipStream_t stream) {
  const float* x  = (const float*)d_in[0];
  const float* wg = (const float*)d_in[1];
  const float* bg = (const float*)d_in[2];
  const float* w1 = (const float*)d_in[3];
  const float* b1 = (const float*)d_in[4];
  const float* w2 = (const float*)d_in[5];
  const float* b2 = (const float*)d_in[6];
  float* out = (float*)d_out;

  char* ws = (char*)d_ws;
  unsigned short* xb = (unsigned short*)ws;   ws += (size_t)B_TOK * D_DIM * 2;
  unsigned short* w1t = (unsigned short*)ws;  ws += (size_t)E_NUM * D_DIM * H_DIM * 2;
  unsigned short* w2t = (unsigned short*)ws;  ws += (size_t)E_NUM * D_DIM * H_DIM * 2;
  unsigned short* Hbuf = (unsigned short*)ws; ws += (size_t)NPAIR * H_DIM * 2;
  int* tidx = (int*)ws;    ws += (size_t)NPAIR * 4;
  float* tgate = (float*)ws; ws += (size_t)NPAIR * 4;
  int* ptok = (int*)ws;    ws += (size_t)NPAIR * 4;
  float* pgate = (float*)ws; ws += (size_t)NPAIR * 4;
  int* meta = (int*)ws;  // cnt[8] | eoff[9] | cursor[8]
  int* cnt = meta;
  int* eoff = meta + 8;
  int* cursor = meta + 17;

  hipMemsetAsync(meta, 0, 32 * sizeof(int), stream);
  hipMemsetAsync(out, 0, (size_t)out_size * sizeof(float), stream);

  k_convert_x<<<(B_TOK * D_DIM) / 1024, 256, 0, stream>>>(x, xb);
  dim3 tb(32, 8);
  k_transpose_bf16<<<dim3(H_DIM / 32, D_DIM / 32, E_NUM), tb, 0, stream>>>(w1, w1t, D_DIM, H_DIM);
  k_transpose_bf16<<<dim3(D_DIM / 32, H_DIM / 32, E_NUM), tb, 0, stream>>>(w2, w2t, H_DIM, D_DIM);
  k_router<<<B_TOK / 4, 256, 0, stream>>>(x, wg, bg, tidx, tgate, cnt);
  k_prefix<<<1, 64, 0, stream>>>(cnt, eoff, cursor);
  k_scatter<<<B_TOK / 256, 256, 0, stream>>>(tidx, tgate, cursor, ptok, pgate);
  k_gemm<D_DIM, H_DIM, 1><<<E_NUM * (NPAIR / 128) * (H_DIM / 128), 256, 0, stream>>>(
      xb, w1t, b1, eoff, ptok, pgate, Hbuf, nullptr);
  k_gemm<H_DIM, D_DIM, 2><<<E_NUM * (NPAIR / 128) * (D_DIM / 128), 256, 0, stream>>>(
      Hbuf, w2t, b2, eoff, ptok, pgate, nullptr, out);
}